// Round 3
// baseline (2152.056 us; speedup 1.0000x reference)
//
#include <hip/hip_runtime.h>

#define DIM   4096
#define NTOK  8192
#define NH    32
#define HD    128

typedef _Float16 f16x8 __attribute__((ext_vector_type(8)));
typedef float    f32x4 __attribute__((ext_vector_type(4)));

__device__ __forceinline__ unsigned short f2h(float f) {
    _Float16 h = (_Float16)f;                    // RTNE
    return __builtin_bit_cast(unsigned short, h);
}
__device__ __forceinline__ float h2f(unsigned short u) {
    return (float)__builtin_bit_cast(_Float16, u);
}

// async 16B/lane global->LDS. LDS dest is wave-uniform base; HW scatters lane L to base + 16*L.
__device__ __forceinline__ void async_ld16(const unsigned short* g, unsigned short* l) {
    __builtin_amdgcn_global_load_lds(
        (const __attribute__((address_space(1))) unsigned int*)g,
        (__attribute__((address_space(3))) unsigned int*)l,
        16, 0, 0);
}

// ---------------------------------------------------------------------------
// x fp32 -> f16, elementwise. 8 elems/thread.
// ---------------------------------------------------------------------------
__global__ __launch_bounds__(256)
void convert_x(const float* __restrict__ in, unsigned short* __restrict__ out) {
    const size_t i = ((size_t)blockIdx.x * 256 + threadIdx.x) * 8;
    float4 a = *(const float4*)(in + i);
    float4 b = *(const float4*)(in + i + 4);
    ushort4 o0 = { f2h(a.x), f2h(a.y), f2h(a.z), f2h(a.w) };
    ushort4 o1 = { f2h(b.x), f2h(b.y), f2h(b.z), f2h(b.w) };
    *(ushort4*)(out + i)     = o0;
    *(ushort4*)(out + i + 4) = o1;
}

// ---------------------------------------------------------------------------
// W fp32 [k][n] -> Wt f16 [n][k], 4096x4096
// ---------------------------------------------------------------------------
__global__ __launch_bounds__(256)
void transpose_cvt4k(const float* __restrict__ in, unsigned short* __restrict__ out) {
    __shared__ unsigned short tile[32][33];
    const int tx = threadIdx.x & 31;
    const int ty = threadIdx.x >> 5;       // 0..7
    const int n0 = blockIdx.x * 32;
    const int k0 = blockIdx.y * 32;
#pragma unroll
    for (int i = 0; i < 4; ++i)
        tile[ty + i * 8][tx] = f2h(in[(size_t)(k0 + ty + i * 8) * DIM + n0 + tx]);
    __syncthreads();
#pragma unroll
    for (int i = 0; i < 4; ++i)
        out[(size_t)(n0 + ty + i * 8) * DIM + k0 + tx] = tile[tx][ty + i * 8];
}

// ---------------------------------------------------------------------------
// NT GEMM: C[M][N] = A[M][K] * Bt[N][K]^T, f16 in, fp32 acc.
// 128x128 tile, 4 waves (2x2), each wave 64x64 = 4x4 MFMA tiles, BK=32.
// OUT_MODE: 0 = fp32, 1 = f16
// ---------------------------------------------------------------------------
template <int OUT_F16>
__global__ __launch_bounds__(256)
void gemm_nt_128(const unsigned short* __restrict__ A,
                 const unsigned short* __restrict__ Bt,
                 void* __restrict__ C, int M, int N, int K) {
    __shared__ unsigned short sA[128 * 32];   // row-major [128][32], no padding (global_load_lds)
    __shared__ unsigned short sB[128 * 32];

    const int t    = threadIdx.x;
    const int w    = t >> 6;
    const int lane = t & 63;
    const int m0   = blockIdx.y * 128;
    const int n0   = blockIdx.x * 128;
    const int wr   = (w >> 1) * 64;           // wave row offset in tile
    const int wc   = (w & 1) * 64;            // wave col offset in tile

    // staging: chunk c = t covers LDS bytes [16c,16c+16) = row (c>>2), cols ((c&3)*8..+8)
    const int r0 = t >> 2;
    const int c8 = (t & 3) * 8;
    const unsigned short* gA0 = A  + (size_t)(m0 + r0) * K + c8;
    const unsigned short* gA1 = gA0 + (size_t)64 * K;
    const unsigned short* gB0 = Bt + (size_t)(n0 + r0) * K + c8;
    const unsigned short* gB1 = gB0 + (size_t)64 * K;
    unsigned short* lA0 = sA + (w * 64) * 8;  // wave-uniform LDS base (64 lanes * 16B per wave)
    unsigned short* lA1 = lA0 + 256 * 8;
    unsigned short* lB0 = sB + (w * 64) * 8;
    unsigned short* lB1 = lB0 + 256 * 8;

    f32x4 acc[4][4];
#pragma unroll
    for (int i = 0; i < 4; ++i)
#pragma unroll
        for (int j = 0; j < 4; ++j) acc[i][j] = (f32x4){0.f, 0.f, 0.f, 0.f};

    const int kq = (lane >> 4) * 8;   // k offset of this lane's 8 contiguous elements
    const int fr = lane & 15;         // fragment row (A: m, B: n)

    const int KT = K >> 5;
    for (int kt = 0; kt < KT; ++kt) {
        __syncthreads();              // previous iter's LDS reads done before overwrite
        const int ko = kt << 5;
        async_ld16(gA0 + ko, lA0);
        async_ld16(gA1 + ko, lA1);
        async_ld16(gB0 + ko, lB0);
        async_ld16(gB1 + ko, lB1);
        asm volatile("s_waitcnt vmcnt(0)" ::: "memory");
        __syncthreads();

        f16x8 aF[4], bF[4];
#pragma unroll
        for (int i = 0; i < 4; ++i)
            aF[i] = *(const f16x8*)(const void*)(sA + (wr + i * 16 + fr) * 32 + kq);
#pragma unroll
        for (int j = 0; j < 4; ++j)
            bF[j] = *(const f16x8*)(const void*)(sB + (wc + j * 16 + fr) * 32 + kq);
#pragma unroll
        for (int i = 0; i < 4; ++i)
#pragma unroll
            for (int j = 0; j < 4; ++j)
                acc[i][j] = __builtin_amdgcn_mfma_f32_16x16x32_f16(aF[i], bF[j], acc[i][j], 0, 0, 0);
    }

    // C/D layout (dtype-independent, verified m89/m91/m121-128): col = lane&15, row = (lane>>4)*4 + reg
    const int col0 = n0 + wc + fr;
    const int row0 = m0 + wr + (lane >> 4) * 4;
#pragma unroll
    for (int i = 0; i < 4; ++i) {
#pragma unroll
        for (int r = 0; r < 4; ++r) {
            const size_t row = (size_t)(row0 + i * 16 + r);
#pragma unroll
            for (int j = 0; j < 4; ++j) {
                const size_t idx = row * (size_t)N + (size_t)(col0 + j * 16);
                if (OUT_F16) ((unsigned short*)C)[idx] = f2h(acc[i][j][r]);
                else         ((float*)C)[idx]          = acc[i][j][r];
            }
        }
    }
}

// ---------------------------------------------------------------------------
// Per-token head-mixing attention: S = Q Kt (32x32), softmax rows, y = S V.
// One block per token. Q,K fp32 (precision), V f16, y f16.
// ---------------------------------------------------------------------------
__global__ __launch_bounds__(256)
void attn_kernel(const float* __restrict__ Q, const float* __restrict__ K,
                 const unsigned short* __restrict__ V, unsigned short* __restrict__ Y) {
    __shared__ float sQ[NH * HD];               // 16 KB
    __shared__ float sK[NH * HD];               // 16 KB
    __shared__ unsigned short sV[NH * HD];      // 8 KB
    __shared__ float sS[NH * 33];               // 32x33 (padded)

    const int n = blockIdx.x;
    const int t = threadIdx.x;
    const size_t base = (size_t)n * DIM;

    const float4* gQ = (const float4*)(Q + base);
    const float4* gK = (const float4*)(K + base);
#pragma unroll
    for (int i = 0; i < 4; ++i) {
        ((float4*)sQ)[t + 256 * i] = gQ[t + 256 * i];
        ((float4*)sK)[t + 256 * i] = gK[t + 256 * i];
    }
    const float4* gV = (const float4*)(V + base);
#pragma unroll
    for (int i = 0; i < 2; ++i)
        ((float4*)sV)[t + 256 * i] = gV[t + 256 * i];
    __syncthreads();

    // scores: 16x16 thread grid, each thread a 2x2 block of S
    {
        const int th = (t >> 4) * 2;
        const int tg = (t & 15) * 2;
        float s00 = 0.f, s01 = 0.f, s10 = 0.f, s11 = 0.f;
        const float4* q0 = (const float4*)(sQ + th * HD);
        const float4* q1 = (const float4*)(sQ + (th + 1) * HD);
        const float4* k0 = (const float4*)(sK + tg * HD);
        const float4* k1 = (const float4*)(sK + (tg + 1) * HD);
#pragma unroll 4
        for (int d = 0; d < HD / 4; ++d) {
            float4 a0 = q0[d], a1 = q1[d], b0 = k0[d], b1 = k1[d];
            s00 += a0.x * b0.x + a0.y * b0.y + a0.z * b0.z + a0.w * b0.w;
            s01 += a0.x * b1.x + a0.y * b1.y + a0.z * b1.z + a0.w * b1.w;
            s10 += a1.x * b0.x + a1.y * b0.y + a1.z * b0.z + a1.w * b0.w;
            s11 += a1.x * b1.x + a1.y * b1.y + a1.z * b1.z + a1.w * b1.w;
        }
        sS[th * 33 + tg] = s00;       sS[th * 33 + tg + 1] = s01;
        sS[(th + 1) * 33 + tg] = s10; sS[(th + 1) * 33 + tg + 1] = s11;
    }
    __syncthreads();

    if (t < NH) {                      // row softmax (no 1/sqrt(d) scale — faithful to ref)
        float m = -1e30f;
        for (int g = 0; g < NH; ++g) m = fmaxf(m, sS[t * 33 + g]);
        float sum = 0.f;
        for (int g = 0; g < NH; ++g) { float e = __expf(sS[t * 33 + g] - m); sS[t * 33 + g] = e; sum += e; }
        float inv = 1.f / sum;
        for (int g = 0; g < NH; ++g) sS[t * 33 + g] *= inv;
    }
    __syncthreads();

    // y[h][d] = sum_g S[h][g] * V[g][d]; thread task: 2 heads x 4 d
#pragma unroll
    for (int e = 0; e < 2; ++e) {
        const int task = t + e * 256;          // 0..511
        const int h0 = (task >> 5) * 2;        // heads h0, h0+1
        const int dg = (task & 31) * 4;        // d offset
        float a0x = 0, a0y = 0, a0z = 0, a0w = 0;
        float a1x = 0, a1y = 0, a1z = 0, a1w = 0;
#pragma unroll 4
        for (int g = 0; g < NH; ++g) {
            ushort4 uv = *(const ushort4*)(const void*)(sV + g * HD + dg);
            float vx = h2f(uv.x), vy = h2f(uv.y), vz = h2f(uv.z), vw = h2f(uv.w);
            float p0 = sS[h0 * 33 + g], p1 = sS[(h0 + 1) * 33 + g];
            a0x += p0 * vx; a0y += p0 * vy; a0z += p0 * vz; a0w += p0 * vw;
            a1x += p1 * vx; a1y += p1 * vy; a1z += p1 * vz; a1w += p1 * vw;
        }
        ushort4 o0 = { f2h(a0x), f2h(a0y), f2h(a0z), f2h(a0w) };
        ushort4 o1 = { f2h(a1x), f2h(a1y), f2h(a1z), f2h(a1w) };
        *(ushort4*)(void*)(Y + base + (size_t)h0 * HD + dg)       = o0;
        *(ushort4*)(void*)(Y + base + (size_t)(h0 + 1) * HD + dg) = o1;
    }
}

// ---------------------------------------------------------------------------
extern "C" void kernel_launch(void* const* d_in, const int* in_sizes, int n_in,
                              void* d_out, int out_size, void* d_ws, size_t ws_size,
                              hipStream_t stream) {
    // Reference dtypes are float32 -> inputs const float*, output float*.
    const float* x  = (const float*)d_in[0];
    const float* Wq = (const float*)d_in[1];
    const float* Wk = (const float*)d_in[2];
    const float* Wv = (const float*)d_in[3];
    const float* Wo = (const float*)d_in[4];
    float* out = (float*)d_out;

    // ws layout (416 MiB total; proven to fit):
    // [Wt f16 32M][xh f16 64M][Qf f32 128M][Kf f32 128M][Vh f16 64M]
    // Yh (f16 64M) overlays xh — x is dead after the V GEMM.
    const size_t WT = (size_t)DIM * DIM * 2;
    const size_t XB = (size_t)NTOK * DIM * 2;
    const size_t QF = (size_t)NTOK * DIM * 4;
    const size_t VB = (size_t)NTOK * DIM * 2;
    const size_t NEED = WT + XB + 2 * QF + VB;    // 416 MiB
    if (ws_size < NEED) return;

    char* ws = (char*)d_ws;
    unsigned short* Wt = (unsigned short*)ws;
    unsigned short* xh = (unsigned short*)(ws + WT);
    float*          Qf = (float*)(ws + WT + XB);
    float*          Kf = (float*)(ws + WT + XB + QF);
    unsigned short* Vh = (unsigned short*)(ws + WT + XB + 2 * QF);
    unsigned short* Yh = xh;                      // overlay

    dim3 tgrid(DIM / 32, DIM / 32);
    dim3 ggrid(DIM / 128, NTOK / 128);
    const int cblocks = (NTOK * DIM) / (256 * 8);

    convert_x<<<cblocks, 256, 0, stream>>>(x, xh);
    transpose_cvt4k<<<tgrid, 256, 0, stream>>>(Wq, Wt);
    gemm_nt_128<0><<<ggrid, 256, 0, stream>>>(xh, Wt, Qf, NTOK, DIM, DIM);
    transpose_cvt4k<<<tgrid, 256, 0, stream>>>(Wk, Wt);
    gemm_nt_128<0><<<ggrid, 256, 0, stream>>>(xh, Wt, Kf, NTOK, DIM, DIM);
    transpose_cvt4k<<<tgrid, 256, 0, stream>>>(Wv, Wt);
    gemm_nt_128<1><<<ggrid, 256, 0, stream>>>(xh, Wt, Vh, NTOK, DIM, DIM);
    attn_kernel<<<NTOK, 256, 0, stream>>>(Qf, Kf, Vh, Yh);   // Yh overlays xh; x no longer needed
    transpose_cvt4k<<<tgrid, 256, 0, stream>>>(Wo, Wt);
    gemm_nt_128<0><<<ggrid, 256, 0, stream>>>(Yh, Wt, out, NTOK, DIM, DIM);
}